// Round 6
// baseline (172.822 us; speedup 1.0000x reference)
//
#include <hip/hip_runtime.h>
#include <hip/hip_bf16.h>
#include <stdint.h>

// OFPenalty: per-batch Gram (49x49 from 2048x49) -> two 9-step power
// iterations -> penalty scalar. Memory-bound on reading x (102.8 MB; floor
// ~16.3 us at 6.3 TB/s). Timed region also contains ~2 harness workspace
// poison fills (~61 us each, 392 MiB) we cannot control from here.
//
// R7: minimal-delta fusion. R4's fusion NaN'd but changed 5 things at once;
// R5 has since hardware-verified the in-register eigen (absmax 0.0). This
// version fuses with the SMALLEST possible step from verified code:
//  - gram pipeline is R3's byte-level structure (256 thr, 4 waves, CHUNK=64,
//    same staging indices, same comp16, 41.6 KB LDS) — only the chunk loop
//    runs 32 chunks (full 2048 k, contiguous; same ascending k order)
//    instead of 8, and the quadrant write targets LDS A instead of the
//    global partial (same indices, same masks).
//  - eigen = R5's verified wave-0 in-register recurrence, unchanged.
//  - removes: 9.85 MB partial write + 9.85 MB re-read, eigen's A-build,
//    one heavyweight dispatch. pen[b] -> ws; 64-thr finish sums -> out.

#define BATCH 256
#define CDIM  2048
#define NDIM  49
#define CHUNK 64                     // k rows per LDS stage
#define NCHUNK (CDIM / CHUNK)        // 32 (full K per block)
#define ITEMS (NDIM * (CHUNK / 8))   // 392 16B k-blocks per chunk
#define CHUNK_FLOATS (CHUNK * NDIM)  // 3136

typedef __bf16 bf16x8 __attribute__((ext_vector_type(8)));
typedef float  f32x16 __attribute__((ext_vector_type(16)));
typedef float  f32x4  __attribute__((ext_vector_type(4)));

union V16 {
  f32x4  f4;
  bf16x8 b8;
};

__device__ __forceinline__ void load8(const float* __restrict__ g,
                                      float (&r)[8]) {
#pragma unroll
  for (int j = 0; j < 8; ++j) r[j] = g[j * NDIM];
}

__device__ __forceinline__ void cvt_store(const float (&r)[8], uint32_t* Hb,
                                          uint32_t* Lb, int w) {
  bf16x8 hv, lv;
#pragma unroll
  for (int j = 0; j < 8; ++j) {
    float e = r[j];
    __bf16 h = (__bf16)e;            // RNE high part
    hv[j] = h;
    lv[j] = (__bf16)(e - (float)h);  // exact residual, then RNE
  }
  V16 a, b;
  a.b8 = hv;
  b.b8 = lv;
  *(f32x4*)(Hb + w) = a.f4;   // ds_write_b128, swizzled slot
  *(f32x4*)(Lb + w) = b.f4;
}

__device__ __forceinline__ void comp16(const uint32_t* Hb, const uint32_t* Lb,
                                       int m, int n, int hf, f32x16& c1,
                                       f32x16& c2, f32x16& c3) {
  const f32x4* H = (const f32x4*)Hb;
  const f32x4* L = (const f32x4*)Lb;
#pragma unroll
  for (int s = 0; s < 4; ++s) {
    const int blk = 2 * s + hf;   // k-halves: kk = s*16 + hf*8
    V16 ah, al, bh, bl;
    ah.f4 = H[m * 8 + (blk ^ (m & 7))];
    al.f4 = L[m * 8 + (blk ^ (m & 7))];
    bh.f4 = H[n * 8 + (blk ^ (n & 7))];
    bl.f4 = L[n * 8 + (blk ^ (n & 7))];
    c1 = __builtin_amdgcn_mfma_f32_32x32x16_bf16(ah.b8, bh.b8, c1, 0, 0, 0);
    c2 = __builtin_amdgcn_mfma_f32_32x32x16_bf16(ah.b8, bl.b8, c2, 0, 0, 0);
    c3 = __builtin_amdgcn_mfma_f32_32x32x16_bf16(al.b8, bh.b8, c3, 0, 0, 0);
  }
}

__global__ __launch_bounds__(256) void fused_kernel(
    const float* __restrict__ x, const float* __restrict__ x0,
    float* __restrict__ pen) {
  // Transposed split-bf16 chunk: row n (0..48, rows 49-63 stale/ignored),
  // 64 bf16 along k = 8 16B-blocks, block index XOR-swizzled by (n&7).
  __shared__ __align__(16) uint32_t ldsHi[2][2048];  // 8 KB per buffer
  __shared__ __align__(16) uint32_t ldsLo[2][2048];
  __shared__ __align__(16) float A[NDIM * NDIM + 3]; // 9.6 KB; total 41.6 KB

  const int tid  = threadIdx.x;
  const int b    = blockIdx.x;        // batch 0..255
  const int lane = tid & 63;
  const int wv   = tid >> 6;          // 0..3
  const int ln   = lane & 31;
  const int hf   = lane >> 5;         // k-half selector
  const int qm = wv >> 1, qn = wv & 1;
  const int m = qm * 32 + ln;         // A row this lane feeds
  const int n = qn * 32 + ln;         // B col this lane feeds

  const float* gbase = x + (size_t)b * (CDIM * NDIM);

  // staging item assignment (constant across chunks): item = kq*49 + n_s
  const int i0 = tid;                       // always < 392
  const int i1 = tid + 256;
  const bool v1 = (i1 < ITEMS);             // tid < 136
  const int kq0 = (i0 * 1338) >> 16;        // exact /49 for i < 2520
  const int n0  = i0 - 49 * kq0;
  const int kq1 = (i1 * 1338) >> 16;
  const int n1  = i1 - 49 * kq1;
  const int g0  = kq0 * (8 * NDIM) + n0;    // float offset of (k=8*kq, n)
  const int g1  = kq1 * (8 * NDIM) + n1;
  const int w0  = n0 * 32 + 4 * (kq0 ^ (n0 & 7));  // u32 slot (swizzled)
  const int w1  = n1 * 32 + 4 * (kq1 ^ (n1 & 7));

  f32x16 c1, c2, c3;
#pragma unroll
  for (int i = 0; i < 16; ++i) { c1[i] = 0.f; c2[i] = 0.f; c3[i] = 0.f; }

  float sA0[8], sA1[8], sB0[8], sB1[8];

  // prologue: chunk 0 -> regs
  load8(gbase + g0, sA0);
  if (v1) load8(gbase + g1, sA1);

  for (int ch = 0; ch < NCHUNK; ch += 2) {
    {  // prefetch chunk ch+1 (in flight across store+barrier+compute)
      const float* gch = gbase + (size_t)(ch + 1) * CHUNK_FLOATS;
      load8(gch + g0, sB0);
      if (v1) load8(gch + g1, sB1);
    }
    cvt_store(sA0, ldsHi[0], ldsLo[0], w0);
    if (v1) cvt_store(sA1, ldsHi[0], ldsLo[0], w1);
    __syncthreads();  // buf0 ready; everyone done reading buf1 (prev iter)
    comp16(ldsHi[0], ldsLo[0], m, n, hf, c1, c2, c3);

    if (ch + 2 < NCHUNK) {
      const float* gch = gbase + (size_t)(ch + 2) * CHUNK_FLOATS;
      load8(gch + g0, sA0);
      if (v1) load8(gch + g1, sA1);
    }
    cvt_store(sB0, ldsHi[1], ldsLo[1], w0);
    if (v1) cvt_store(sB1, ldsHi[1], ldsLo[1], w1);
    __syncthreads();  // buf1 ready; everyone done reading buf0
    comp16(ldsHi[1], ldsLo[1], m, n, hf, c1, c2, c3);
  }

  // quadrant write -> LDS A (same indices/masks as verified partial write)
  // C/D layout (m74/m101): col = lane&31, row = (reg&3)+8*(reg>>2)+4*(lane>>5)
#pragma unroll
  for (int r = 0; r < 16; ++r) {
    int row = (r & 3) + 8 * (r >> 2) + 4 * hf;
    int mm = qm * 32 + row;
    if (mm < NDIM && n < NDIM)
      A[mm * NDIM + n] = c1[r] + c2[r] + c3[r];
  }
  __syncthreads();

  // ---- power iteration: wave 0 only, fully in-register (R5-verified) ----
  if (tid < 64) {
    const bool act = (tid < NDIM);
    float Ar[NDIM];
    {
      const float* Arow = &A[(act ? tid : (NDIM - 1)) * NDIM];
#pragma unroll
      for (int k = 0; k < NDIM; ++k) Ar[k] = Arow[k];
    }
    float xl = act ? x0[b * NDIM + tid] : 0.f;

    // 9x {x = normalize((A - sI) x)}, then Rayleigh num/den on one more
    // matvec. xl stays as final x (warm start for 2nd call).
    auto rayleigh = [&](float shift) -> float {
      for (int it = 0; it < 9; ++it) {
        float a0 = 0.f, a1 = 0.f, a2 = 0.f, a3 = 0.f;
#pragma unroll
        for (int k = 0; k < 48; k += 4) {
          a0 = fmaf(Ar[k + 0], __shfl(xl, k + 0, 64), a0);
          a1 = fmaf(Ar[k + 1], __shfl(xl, k + 1, 64), a1);
          a2 = fmaf(Ar[k + 2], __shfl(xl, k + 2, 64), a2);
          a3 = fmaf(Ar[k + 3], __shfl(xl, k + 3, 64), a3);
        }
        a0 = fmaf(Ar[48], __shfl(xl, 48, 64), a0);
        float y = act ? (((a0 + a1) + (a2 + a3)) - shift * xl) : 0.f;
        float s2 = y * y;
#pragma unroll
        for (int o = 32; o; o >>= 1) s2 += __shfl_xor(s2, o, 64);
        xl = y / fmaxf(sqrtf(s2), 1e-12f);  // F.normalize eps
      }
      float a0 = 0.f, a1 = 0.f, a2 = 0.f, a3 = 0.f;
#pragma unroll
      for (int k = 0; k < 48; k += 4) {
        a0 = fmaf(Ar[k + 0], __shfl(xl, k + 0, 64), a0);
        a1 = fmaf(Ar[k + 1], __shfl(xl, k + 1, 64), a1);
        a2 = fmaf(Ar[k + 2], __shfl(xl, k + 2, 64), a2);
        a3 = fmaf(Ar[k + 3], __shfl(xl, k + 3, 64), a3);
      }
      a0 = fmaf(Ar[48], __shfl(xl, 48, 64), a0);
      float yy = act ? (((a0 + a1) + (a2 + a3)) - shift * xl) : 0.f;
      float num = yy * xl;
      float den = xl * xl;
#pragma unroll
      for (int o = 32; o; o >>= 1) {
        num += __shfl_xor(num, o, 64);
        den += __shfl_xor(den, o, 64);
      }
      return num / den;
    };

    float largest  = rayleigh(0.f);
    float smallest = rayleigh(largest) + largest;  // warm start: xl == x1
    if (tid == 0) {
      float r = largest / smallest - 1.f;
      pen[b] = r * r;
    }
  }
}

__global__ __launch_bounds__(64) void finish_kernel(
    const float* __restrict__ pen, float* __restrict__ out) {
  const int t = threadIdx.x;
  float s = pen[t] + pen[t + 64] + pen[t + 128] + pen[t + 192];
#pragma unroll
  for (int o = 32; o; o >>= 1) s += __shfl_xor(s, o, 64);
  if (t == 0) out[0] = s * (1.0f / (float)BATCH);  // BETA = 1
}

extern "C" void kernel_launch(void* const* d_in, const int* in_sizes, int n_in,
                              void* d_out, int out_size, void* d_ws,
                              size_t ws_size, hipStream_t stream) {
  const float* x  = (const float*)d_in[0];   // [256,2048,7,7] fp32
  const float* x0 = (const float*)d_in[1];   // [256,49,1] fp32 (pre-normalized)
  float* out = (float*)d_out;                // scalar fp32
  float* pen = (float*)d_ws;                 // 256 fp32 per-batch penalties

  fused_kernel<<<BATCH, 256, 0, stream>>>(x, x0, pen);
  finish_kernel<<<1, 64, 0, stream>>>(pen, out);
}

// Round 7
// 168.320 us; speedup vs baseline: 1.0268x; 1.0268x over previous
//
#include <hip/hip_runtime.h>
#include <hip/hip_bf16.h>
#include <stdint.h>

// OFPenalty: per-batch Gram (49x49 from 2048x49) -> two 9-step power
// iterations -> penalty scalar. Memory-bound on reading x (102.8 MB; floor
// ~16.3 us at 6.3 TB/s). Timed region also contains harness workspace
// poison fills (~61 us each) we cannot control from here.
//
// R8: occupancy fix for the fused kernel. R7 (verified correct, absmax 0.0)
// ran at 1 wave/SIMD -> 63 us even with warm caches (FETCH 8 KB replay also
// 63 us): pure latency exposure, not BW. This version keeps the fused
// structure but restores R3's 4 waves/SIMD:
//  - 256 blocks x 1024 threads: 4 K-groups x 4 waves; group g = R3's
//    verified pipeline verbatim on K-quarter g (same staging indices,
//    CHUNK=64, double-buffered, same comp16). Wave w -> SIMD w&3, so each
//    SIMD interleaves one wave of each group.
//  - LDS: flat 128 KiB (4 groups x 2 bufs x (Hi 8K + Lo 8K)) — exactly the
//    verified-on-gfx950 static-LDS maximum precedent. A (9.6 KB) aliases
//    group 0's buffers after the final barrier (all reads done).
//  - A accumulate: g0 write, g1 +=, g2 +=, g3 += (barrier-separated) ==
//    R5's quarter-sum order ((q0+q1)+q2)+q3 bit-exactly.
//  - eigen: R5-verified wave-0 in-register recurrence, unchanged.
//  - R4's NaN root cause (now explained): 137.7 KB static LDS > 128 KiB
//    envelope -> launch failure -> NaN-poisoned ws read by finish.

#define BATCH 256
#define CDIM  2048
#define NDIM  49
#define GROUPS 4
#define GK    (CDIM / GROUPS)        // 512 k-rows per group (== R3's QK)
#define CHUNK 64                     // k rows per LDS stage
#define NCHUNK (GK / CHUNK)          // 8 chunks per group
#define ITEMS (NDIM * (CHUNK / 8))   // 392 16B k-blocks per chunk
#define CHUNK_FLOATS (CHUNK * NDIM)  // 3136

typedef __bf16 bf16x8 __attribute__((ext_vector_type(8)));
typedef float  f32x16 __attribute__((ext_vector_type(16)));
typedef float  f32x4  __attribute__((ext_vector_type(4)));

union V16 {
  f32x4  f4;
  bf16x8 b8;
};

__device__ __forceinline__ void load8(const float* __restrict__ g,
                                      float (&r)[8]) {
#pragma unroll
  for (int j = 0; j < 8; ++j) r[j] = g[j * NDIM];
}

__device__ __forceinline__ void cvt_store(const float (&r)[8], float* Hb,
                                          float* Lb, int w) {
  bf16x8 hv, lv;
#pragma unroll
  for (int j = 0; j < 8; ++j) {
    float e = r[j];
    __bf16 h = (__bf16)e;            // RNE high part
    hv[j] = h;
    lv[j] = (__bf16)(e - (float)h);  // exact residual, then RNE
  }
  V16 a, b;
  a.b8 = hv;
  b.b8 = lv;
  *(f32x4*)(Hb + w) = a.f4;   // ds_write_b128, swizzled slot
  *(f32x4*)(Lb + w) = b.f4;
}

__device__ __forceinline__ void comp16(const float* Hb, const float* Lb,
                                       int m, int n, int hf, f32x16& c1,
                                       f32x16& c2, f32x16& c3) {
  const f32x4* H = (const f32x4*)Hb;
  const f32x4* L = (const f32x4*)Lb;
#pragma unroll
  for (int s = 0; s < 4; ++s) {
    const int blk = 2 * s + hf;   // k-halves: kk = s*16 + hf*8
    V16 ah, al, bh, bl;
    ah.f4 = H[m * 8 + (blk ^ (m & 7))];
    al.f4 = L[m * 8 + (blk ^ (m & 7))];
    bh.f4 = H[n * 8 + (blk ^ (n & 7))];
    bl.f4 = L[n * 8 + (blk ^ (n & 7))];
    c1 = __builtin_amdgcn_mfma_f32_32x32x16_bf16(ah.b8, bh.b8, c1, 0, 0, 0);
    c2 = __builtin_amdgcn_mfma_f32_32x32x16_bf16(ah.b8, bl.b8, c2, 0, 0, 0);
    c3 = __builtin_amdgcn_mfma_f32_32x32x16_bf16(al.b8, bh.b8, c3, 0, 0, 0);
  }
}

__global__ __launch_bounds__(1024) void fused_kernel(
    const float* __restrict__ x, const float* __restrict__ x0,
    float* __restrict__ pen) {
  // 128 KiB flat LDS. Group g, buffer b: Hi = lds + g*8192 + b*4096,
  // Lo = Hi + 2048 (units: floats/u32). Layout within a buffer identical
  // to R3: row n (0..48; 49-63 stale, masked at A-write), 8 16B k-blocks,
  // block index XOR-swizzled by (n&7).
  __shared__ __align__(16) float lds[32768];

  const int tid  = threadIdx.x;       // 0..1023
  const int b    = blockIdx.x;        // batch 0..255
  const int g    = tid >> 8;          // K-group 0..3
  const int ltid = tid & 255;         // thread within group (== R3 tid)
  const int lane = tid & 63;
  const int gw   = (tid >> 6) & 3;    // wave within group -> quadrant
  const int ln   = lane & 31;
  const int hf   = lane >> 5;         // k-half selector
  const int qm = gw >> 1, qn = gw & 1;
  const int m = qm * 32 + ln;         // A row this lane feeds
  const int n = qn * 32 + ln;         // B col this lane feeds

  float* const buf0 = lds + g * 8192;          // Hi0 (Lo0 = +2048)
  float* const buf1 = lds + g * 8192 + 4096;   // Hi1 (Lo1 = +2048)

  const float* gbase = x + (size_t)b * (CDIM * NDIM)
                         + (size_t)g * (GK * NDIM);

  // staging item assignment (constant across chunks): item = kq*49 + n_s
  const int i0 = ltid;                      // always < 392
  const int i1 = ltid + 256;
  const bool v1 = (i1 < ITEMS);             // ltid < 136
  const int kq0 = (i0 * 1338) >> 16;        // exact /49 for i < 2520
  const int n0  = i0 - 49 * kq0;
  const int kq1 = (i1 * 1338) >> 16;
  const int n1  = i1 - 49 * kq1;
  const int g0  = kq0 * (8 * NDIM) + n0;    // float offset of (k=8*kq, n)
  const int g1  = kq1 * (8 * NDIM) + n1;
  const int w0  = n0 * 32 + 4 * (kq0 ^ (n0 & 7));  // slot (swizzled)
  const int w1  = n1 * 32 + 4 * (kq1 ^ (n1 & 7));

  f32x16 c1, c2, c3;
#pragma unroll
  for (int i = 0; i < 16; ++i) { c1[i] = 0.f; c2[i] = 0.f; c3[i] = 0.f; }

  float sA0[8], sA1[8], sB0[8], sB1[8];

  // prologue: chunk 0 -> regs
  load8(gbase + g0, sA0);
  if (v1) load8(gbase + g1, sA1);

#pragma unroll
  for (int ch = 0; ch < NCHUNK; ch += 2) {
    {  // prefetch chunk ch+1 (hides HBM latency under cvt+barrier+compute)
      const float* gch = gbase + (size_t)(ch + 1) * CHUNK_FLOATS;
      load8(gch + g0, sB0);
      if (v1) load8(gch + g1, sB1);
    }
    cvt_store(sA0, buf0, buf0 + 2048, w0);
    if (v1) cvt_store(sA1, buf0, buf0 + 2048, w1);
    __syncthreads();  // buf0 ready; everyone done reading buf1 (prev iter)
    comp16(buf0, buf0 + 2048, m, n, hf, c1, c2, c3);

    if (ch + 2 < NCHUNK) {
      const float* gch = gbase + (size_t)(ch + 2) * CHUNK_FLOATS;
      load8(gch + g0, sA0);
      if (v1) load8(gch + g1, sA1);
    }
    cvt_store(sB0, buf1, buf1 + 2048, w0);
    if (v1) cvt_store(sB1, buf1, buf1 + 2048, w1);
    __syncthreads();  // buf1 ready; everyone done reading buf0
    comp16(buf1, buf1 + 2048, m, n, hf, c1, c2, c3);
  }

  // A aliases lds[0..2403] (group 0's buffers — all reads complete).
  // Accumulate groups in ascending-k order: bit-identical to R5's
  // quarter-sum ((q0+q1)+q2)+q3.
  float* A = lds;
  __syncthreads();  // all comp16 reads done before A overwrites buffers
#pragma unroll
  for (int gg = 0; gg < GROUPS; ++gg) {
    if (g == gg) {
#pragma unroll
      for (int r = 0; r < 16; ++r) {
        int row = (r & 3) + 8 * (r >> 2) + 4 * hf;
        int mm = qm * 32 + row;
        if (mm < NDIM && n < NDIM) {
          float v = c1[r] + c2[r] + c3[r];
          if (gg == 0) A[mm * NDIM + n] = v;
          else         A[mm * NDIM + n] += v;
        }
      }
    }
    __syncthreads();
  }

  // ---- power iteration: wave 0 only, fully in-register (R5-verified) ----
  if (tid < 64) {
    const bool act = (tid < NDIM);
    float Ar[NDIM];
    {
      const float* Arow = &A[(act ? tid : (NDIM - 1)) * NDIM];
#pragma unroll
      for (int k = 0; k < NDIM; ++k) Ar[k] = Arow[k];
    }
    float xl = act ? x0[b * NDIM + tid] : 0.f;

    // 9x {x = normalize((A - sI) x)}, then Rayleigh num/den on one more
    // matvec. xl stays as final x (warm start for 2nd call).
    auto rayleigh = [&](float shift) -> float {
      for (int it = 0; it < 9; ++it) {
        float a0 = 0.f, a1 = 0.f, a2 = 0.f, a3 = 0.f;
#pragma unroll
        for (int k = 0; k < 48; k += 4) {
          a0 = fmaf(Ar[k + 0], __shfl(xl, k + 0, 64), a0);
          a1 = fmaf(Ar[k + 1], __shfl(xl, k + 1, 64), a1);
          a2 = fmaf(Ar[k + 2], __shfl(xl, k + 2, 64), a2);
          a3 = fmaf(Ar[k + 3], __shfl(xl, k + 3, 64), a3);
        }
        a0 = fmaf(Ar[48], __shfl(xl, 48, 64), a0);
        float y = act ? (((a0 + a1) + (a2 + a3)) - shift * xl) : 0.f;
        float s2 = y * y;
#pragma unroll
        for (int o = 32; o; o >>= 1) s2 += __shfl_xor(s2, o, 64);
        xl = y / fmaxf(sqrtf(s2), 1e-12f);  // F.normalize eps
      }
      float a0 = 0.f, a1 = 0.f, a2 = 0.f, a3 = 0.f;
#pragma unroll
      for (int k = 0; k < 48; k += 4) {
        a0 = fmaf(Ar[k + 0], __shfl(xl, k + 0, 64), a0);
        a1 = fmaf(Ar[k + 1], __shfl(xl, k + 1, 64), a1);
        a2 = fmaf(Ar[k + 2], __shfl(xl, k + 2, 64), a2);
        a3 = fmaf(Ar[k + 3], __shfl(xl, k + 3, 64), a3);
      }
      a0 = fmaf(Ar[48], __shfl(xl, 48, 64), a0);
      float yy = act ? (((a0 + a1) + (a2 + a3)) - shift * xl) : 0.f;
      float num = yy * xl;
      float den = xl * xl;
#pragma unroll
      for (int o = 32; o; o >>= 1) {
        num += __shfl_xor(num, o, 64);
        den += __shfl_xor(den, o, 64);
      }
      return num / den;
    };

    float largest  = rayleigh(0.f);
    float smallest = rayleigh(largest) + largest;  // warm start: xl == x1
    if (tid == 0) {
      float r = largest / smallest - 1.f;
      pen[b] = r * r;
    }
  }
}

__global__ __launch_bounds__(64) void finish_kernel(
    const float* __restrict__ pen, float* __restrict__ out) {
  const int t = threadIdx.x;
  float s = pen[t] + pen[t + 64] + pen[t + 128] + pen[t + 192];
#pragma unroll
  for (int o = 32; o; o >>= 1) s += __shfl_xor(s, o, 64);
  if (t == 0) out[0] = s * (1.0f / (float)BATCH);  // BETA = 1
}

extern "C" void kernel_launch(void* const* d_in, const int* in_sizes, int n_in,
                              void* d_out, int out_size, void* d_ws,
                              size_t ws_size, hipStream_t stream) {
  const float* x  = (const float*)d_in[0];   // [256,2048,7,7] fp32
  const float* x0 = (const float*)d_in[1];   // [256,49,1] fp32 (pre-normalized)
  float* out = (float*)d_out;                // scalar fp32
  float* pen = (float*)d_ws;                 // 256 fp32 per-batch penalties

  fused_kernel<<<BATCH, 1024, 0, stream>>>(x, x0, pen);
  finish_kernel<<<1, 64, 0, stream>>>(pen, out);
}